// Round 12
// baseline (106.143 us; speedup 1.0000x reference)
//
#include <hip/hip_runtime.h>
#include <hip/hip_bf16.h>

typedef __attribute__((ext_vector_type(8)))  short short8;
typedef __attribute__((ext_vector_type(4)))  float f32x4;

#define NR 256
#define CC 256

__device__ __forceinline__ unsigned short f2bf(float x) {
    union { float f; unsigned int u; } v; v.f = x;
    unsigned int r = v.u + 0x7FFFu + ((v.u >> 16) & 1u);
    return (unsigned short)(r >> 16);
}

__device__ __forceinline__ unsigned int pk2bf(float a, float b) {
    __hip_bfloat162 h = __float22bfloat162_rn(make_float2(a, b));
    union { __hip_bfloat162 h; unsigned int u; } cv; cv.h = h;
    return cv.u;
}

// ---------------- setup: qp (bx<16) | wvp_pack (bx<81) | mlp pack 16x16 layout (else) ----------------
__global__ __launch_bounds__(256) void setup_kernel(
    const float* __restrict__ Q, const float* __restrict__ Wq, float* __restrict__ Qpp,
    const float* __restrict__ Wv, unsigned short* __restrict__ wvp,
    const float* __restrict__ W01, const float* __restrict__ W1,
    const float* __restrict__ W02, const float* __restrict__ W2,
    unsigned short* __restrict__ wpa, unsigned short* __restrict__ wpb)
{
    __shared__ float tile[32][260];
    __shared__ float qs[256];
    const int bx = blockIdx.x;
    const int tid = threadIdx.x;

    if (bx < 16) {                       // ---- Qpp[ksl][b][n] = partial Q @ Wq
        int ksl = bx & 3, b = bx >> 2;
        qs[tid] = Q[b * 1024 + ksl * 256 + tid];
        __syncthreads();
        float acc = 0.f;
        #pragma unroll 4
        for (int d = 0; d < 256; ++d) acc += qs[d] * Wq[(size_t)(ksl * 256 + d) * 256 + tid];
        Qpp[(ksl * 4 + b) * 256 + tid] = acc;
    } else if (bx < 81) {                // ---- Wv -> 16x16x32 B-frag layout, K pad 2080
        int ks = bx - 16;                // 0..64
        for (int idx = tid; idx < 32 * 256; idx += 256) {
            int cr = idx >> 8, n = idx & 255;
            int c = ks * 32 + cr;
            tile[cr][n] = (c < 2056) ? Wv[(size_t)c * 256 + n] : 0.f;
        }
        __syncthreads();
        #pragma unroll
        for (int q = 0; q < 4; ++q) {
            int t2 = tid * 4 + q;
            int nt = t2 >> 6, l = t2 & 63;
            int gg = l >> 4, jj = l & 15;
            short8 s;
            #pragma unroll
            for (int e = 0; e < 8; ++e)
                s[e] = (short)f2bf(tile[gg * 8 + e][nt * 16 + jj]);
            *(short8*)&wvp[((size_t)(ks * 16 + nt) * 64 + l) * 8] = s;
        }
    } else {                             // ---- MLP weights -> 16x16x32 A-frag layout (r2-proven)
        // wpa: [br][nt(8)][ks(8)][lane(64)][e(8)]  = W[c=32ks+8*(l>>4)+e][n=16nt+(l&15)]
        // wpb: [br][nt(4)][ks(4)][lane(64)][e(8)]
        int t = (bx - 81) * 256 + tid;   // < 81920
        if (t < 65536) {
            int e = t & 7, l = (t >> 3) & 63, ks = (t >> 9) & 7, nt = (t >> 12) & 7, br = (t >> 15) & 1;
            int cc = ks * 32 + (l >> 4) * 8 + e;
            int n = nt * 16 + (l & 15);
            const float* W = br ? W1 : W01;
            wpa[t] = f2bf(W[cc * 128 + n]);
        } else {
            int t2 = t - 65536;          // < 16384
            int e = t2 & 7, l = (t2 >> 3) & 63, ks = (t2 >> 9) & 3, nt = (t2 >> 11) & 3, br = (t2 >> 13) & 1;
            int cc = ks * 32 + (l >> 4) * 8 + e;
            int n = nt * 16 + (l & 15);
            const float* W = br ? W2 : W02;
            wpb[t2] = f2bf(W[cc * 64 + n]);
        }
    }
}

// ---------------- Xp (MFMA, 8-wave split-K); each block covers 128 cols ----------------
// r11 had 8 bn-blocks re-reading the same X rows -> 67 MB HBM (~11 us floor).
// Now grid (16 mt, 2 bn2, 4 b) = 128 blocks, X read 2x = 17 MB.
__global__ __launch_bounds__(512) void xp_kernel(
    const float* __restrict__ X, const unsigned short* __restrict__ wvp,
    const float* __restrict__ bv, const float* __restrict__ bq,
    const float* __restrict__ Qpp, float* __restrict__ Xp)
{
    __shared__ f32x4 red[8][8][65];
    const int tid = threadIdx.x;
    const int w = tid >> 6;           // 0..7
    const int lane = tid & 63;
    const int g = lane >> 4, j16v = lane & 15;
    const int mt = blockIdx.x;        // 16-row tile
    const int bn2 = blockIdx.y;       // 0..1 (128-col group)
    const int b  = blockIdx.z;

    const int i0 = mt * 16;
    const float* xrow = X + ((size_t)(b * NR) + (i0 + j16v)) * 2052;

    f32x4 acc[8] = {};

    for (int ks = w; ks < 64; ks += 8) {
        const int c0 = ks * 32 + g * 8;
        float4 xa = *(const float4*)(xrow + c0);
        float4 xb = *(const float4*)(xrow + c0 + 4);
        union { short8 s; unsigned int u[4]; } af;
        af.u[0] = pk2bf(xa.x, xa.y);
        af.u[1] = pk2bf(xa.z, xa.w);
        af.u[2] = pk2bf(xb.x, xb.y);
        af.u[3] = pk2bf(xb.z, xb.w);
        #pragma unroll
        for (int nt = 0; nt < 8; ++nt) {
            short8 bf = ((const short8*)wvp)[(size_t)(ks * 16 + bn2 * 8 + nt) * 64 + lane];
            acc[nt] = __builtin_amdgcn_mfma_f32_16x16x32_bf16(af.s, bf, acc[nt], 0, 0, 0);
        }
    }
    if (w == 0) {  // ks = 64 tail: c 2048..2079 (c>=2056 zero-weighted)
        float xv[8];
        #pragma unroll
        for (int e = 0; e < 8; ++e) {
            int q = g * 8 + e;
            int csrc = (q < 4) ? (2048 + q) : (q - 4);
            xv[e] = xrow[csrc];
        }
        union { short8 s; unsigned int u[4]; } af;
        af.u[0] = pk2bf(xv[0], xv[1]);
        af.u[1] = pk2bf(xv[2], xv[3]);
        af.u[2] = pk2bf(xv[4], xv[5]);
        af.u[3] = pk2bf(xv[6], xv[7]);
        #pragma unroll
        for (int nt = 0; nt < 8; ++nt) {
            short8 bf = ((const short8*)wvp)[(size_t)(64 * 16 + bn2 * 8 + nt) * 64 + lane];
            acc[nt] = __builtin_amdgcn_mfma_f32_16x16x32_bf16(af.s, bf, acc[nt], 0, 0, 0);
        }
    }
    #pragma unroll
    for (int nt = 0; nt < 8; ++nt) red[w][nt][lane] = acc[nt];
    __syncthreads();

    for (int idx = tid; idx < 2048; idx += 512) {
        int nt = idx >> 8, rem = idx & 255;
        int l = rem & 63, reg = rem >> 6;
        float rsum = 0.f;
        #pragma unroll
        for (int ww = 0; ww < 8; ++ww) rsum += red[ww][nt][l][reg];
        int gg = l >> 4, jj = l & 15;
        int n = bn2 * 128 + nt * 16 + jj;
        float base = bv[n] + bq[n] + Qpp[b * 256 + n] + Qpp[(4 + b) * 256 + n]
                   + Qpp[(8 + b) * 256 + n] + Qpp[(12 + b) * 256 + n];
        int row = i0 + gg * 4 + reg;
        Xp[((b * NR) + row) * CC + n] = rsum + base;
    }
}

// ---------------- fused 3-layer MLP over pairs: 16x16 MFMA, K-split W1, low-reg waves ----------------
// block = (b, br, it8 in [0,32) [8 i's, one per wave], jt16 in [it8/2, 16)); 2176 blocks.
// r11 analysis: per-SIMD reg pool ~512/wave-slot; 32x32 wave state ~192 regs -> 2.67 waves/SIMD
// (= measured 33% occupancy). 16x16 fragments: acc1[8]=32 + acc2[4]=16 + bfr(half-K)[4]=16
// -> total ~110 -> 4 waves/SIMD. LDS: W1 in two 32KB K-half stages + W2 16KB + si 8KB ~ 58KB
// -> 2 blocks/CU = 16 waves/CU. Fragment/shuffle machinery identical to r2 (refchecked).
__global__ __launch_bounds__(512, 2) void pairs_kernel(
    const float* __restrict__ Xp,
    const unsigned short* __restrict__ wpa,
    const unsigned short* __restrict__ wpb,
    const float* __restrict__ b01, const float* __restrict__ b02,
    const float* __restrict__ b03,
    const float* __restrict__ b1,  const float* __restrict__ b2,
    const float* __restrict__ b3,
    const float* __restrict__ W03, const float* __restrict__ W3,
    float* __restrict__ colpart, float* __restrict__ rowpart)
{
    __shared__ __align__(16) unsigned short lds_wa[16384];   // 32 KB: W1 one K-half
    __shared__ __align__(16) unsigned short lds_wb[8192];    // 16 KB: W2 full (this branch)
    __shared__ __align__(16) float lds_si[2048];             // 8 i-rows of Xp (f32)
    __shared__ __align__(16) float lds_bias1[128];
    __shared__ __align__(16) float lds_bias2[64];
    __shared__ __align__(16) float lds_w3[64];
    __shared__ float lds_c[8][17];

    const int tid = threadIdx.x;
    const int wave = tid >> 6;       // 0..7
    const int lane = tid & 63;
    const int g = lane >> 4;         // 0..3
    const int j16 = lane & 15;

    // grid decode: bx -> (b, br, it8, jt16); 272 tiles per (b,br)
    int bx = blockIdx.x;
    int b = bx / 544;
    int r = bx - b * 544;
    int br = r / 272;
    int u = r - br * 272;
    int k = 0, off = 0;
    while (k < 15) {
        int cnt = 2 * (16 - k);
        if (u < off + cnt) break;
        off += cnt; ++k;
    }
    int rel = u - off, wdt = 16 - k;
    int it8 = 2 * k + rel / wdt;      // 0..31
    int jt16 = k + rel % wdt;         // it8/2 .. 15

    const int i = it8 * 8 + wave;
    const int blk = br * 4 + b;
    const int j = jt16 * 16 + j16;

    // each wave stages its OWN si row (same-wave RAW, no barrier needed)
    *(float4*)&lds_si[wave * 256 + lane * 4] =
        *(const float4*)&Xp[((b * NR) + i) * CC + lane * 4];

    const uint4* gwa = (const uint4*)wpa + (size_t)br * 4096;   // branch base, 16B units

    // phase 1: stage W1 half0 (ks 0..3 per nt) + W2 + biases
    {
        uint4* s1 = (uint4*)lds_wa;
        #pragma unroll
        for (int it = 0; it < 4; ++it) {
            int q = it * 512 + tid;
            int nt = q >> 8, ksl = (q >> 6) & 3, le = q & 63;
            s1[q] = gwa[(nt * 8 + ksl) * 64 + le];
        }
        const uint4* g2 = (const uint4*)wpb + (size_t)br * 1024;
        uint4* s2 = (uint4*)lds_wb;
        s2[tid] = g2[tid];
        s2[512 + tid] = g2[512 + tid];
        if (tid < 128) lds_bias1[tid] = br ? b1[tid] : b01[tid];
        else if (tid < 192) lds_bias2[tid - 128] = br ? b2[tid - 128] : b02[tid - 128];
        else if (tid < 256) lds_w3[tid - 192] = br ? W3[tid - 192] : W03[tid - 192];
    }
    const float b3v = br ? b3[0] : b03[0];
    const float* si = lds_si + wave * 256;
    const float* xr = Xp + ((size_t)(b * NR) + j) * CC;

    // bfr half0: lane j, k = 32ks + 8g + e, k in [0,128)
    short8 bfr[4];
    #pragma unroll
    for (int ksl = 0; ksl < 4; ++ksl) {
        const int c0 = ksl * 32 + g * 8;
        float4 xa = *(const float4*)(xr + c0);
        float4 xb = *(const float4*)(xr + c0 + 4);
        float4 sa = *(const float4*)(si + c0);
        float4 sb = *(const float4*)(si + c0 + 4);
        union { short8 s; unsigned int uu[4]; } f;
        f.uu[0] = pk2bf(xa.x * sa.x, xa.y * sa.y);
        f.uu[1] = pk2bf(xa.z * sa.z, xa.w * sa.w);
        f.uu[2] = pk2bf(xb.x * sb.x, xb.y * sb.y);
        f.uu[3] = pk2bf(xb.z * sb.z, xb.w * sb.w);
        bfr[ksl] = f.s;
    }
    __syncthreads();

    // acc1 init from bias1 (C/D row = 4g+reg)
    f32x4 acc1[8];
    #pragma unroll
    for (int nt = 0; nt < 8; ++nt)
        acc1[nt] = *(const f32x4*)&lds_bias1[nt * 16 + g * 4];

    // L1 half0: ks-outer / nt-inner (8 independent chains)
    #pragma unroll
    for (int ksl = 0; ksl < 4; ++ksl) {
        const short8 bb = bfr[ksl];
        #pragma unroll
        for (int nt = 0; nt < 8; ++nt) {
            short8 wf = ((const short8*)lds_wa)[(nt * 4 + ksl) * 64 + lane];
            acc1[nt] = __builtin_amdgcn_mfma_f32_16x16x32_bf16(wf, bb, acc1[nt], 0, 0, 0);
        }
    }
    __syncthreads();   // all waves done reading half0

    // phase 2: stage W1 half1 (ks 4..7 per nt); rebuild bfr for k in [128,256)
    {
        uint4* s1 = (uint4*)lds_wa;
        #pragma unroll
        for (int it = 0; it < 4; ++it) {
            int q = it * 512 + tid;
            int nt = q >> 8, ksl = (q >> 6) & 3, le = q & 63;
            s1[q] = gwa[(nt * 8 + 4 + ksl) * 64 + le];
        }
    }
    #pragma unroll
    for (int ksl = 0; ksl < 4; ++ksl) {
        const int c0 = 128 + ksl * 32 + g * 8;
        float4 xa = *(const float4*)(xr + c0);
        float4 xb = *(const float4*)(xr + c0 + 4);
        float4 sa = *(const float4*)(si + c0);
        float4 sb = *(const float4*)(si + c0 + 4);
        union { short8 s; unsigned int uu[4]; } f;
        f.uu[0] = pk2bf(xa.x * sa.x, xa.y * sa.y);
        f.uu[1] = pk2bf(xa.z * sa.z, xa.w * sa.w);
        f.uu[2] = pk2bf(xb.x * sb.x, xb.y * sb.y);
        f.uu[3] = pk2bf(xb.z * sb.z, xb.w * sb.w);
        bfr[ksl] = f.s;
    }
    __syncthreads();

    // L1 half1
    #pragma unroll
    for (int ksl = 0; ksl < 4; ++ksl) {
        const short8 bb = bfr[ksl];
        #pragma unroll
        for (int nt = 0; nt < 8; ++nt) {
            short8 wf = ((const short8*)lds_wa)[(nt * 4 + ksl) * 64 + lane];
            acc1[nt] = __builtin_amdgcn_mfma_f32_16x16x32_bf16(wf, bb, acc1[nt], 0, 0, 0);
        }
    }

    // ---- layer 2 (r2 shuffle-exchange, verbatim): 4 t-steps, W2 frags from LDS ----
    f32x4 acc2[4];
    #pragma unroll
    for (int nt2 = 0; nt2 < 4; ++nt2)
        acc2[nt2] = *(const f32x4*)&lds_bias2[nt2 * 16 + g * 4];

    const int sl0 = ((lane & 16) ? 32 : 0) + j16;
    const int sl1 = sl0 + 16;
    const bool hiL = (g >> 1);

    #pragma unroll
    for (int t = 0; t < 4; ++t) {
        float e0 = fmaxf(acc1[2*t][0], 0.f),   e1 = fmaxf(acc1[2*t][1], 0.f);
        float e2 = fmaxf(acc1[2*t][2], 0.f),   e3 = fmaxf(acc1[2*t][3], 0.f);
        float o0 = fmaxf(acc1[2*t+1][0], 0.f), o1 = fmaxf(acc1[2*t+1][1], 0.f);
        float o2 = fmaxf(acc1[2*t+1][2], 0.f), o3 = fmaxf(acc1[2*t+1][3], 0.f);
        unsigned int uE0 = pk2bf(e0, e1), uE1 = pk2bf(e2, e3);
        unsigned int uO0 = pk2bf(o0, o1), uO1 = pk2bf(o2, o3);
        unsigned int aE0 = __shfl(uE0, sl0, 64), aO0 = __shfl(uO0, sl0, 64);
        unsigned int aE1 = __shfl(uE1, sl0, 64), aO1 = __shfl(uO1, sl0, 64);
        unsigned int bE0 = __shfl(uE0, sl1, 64), bO0 = __shfl(uO0, sl1, 64);
        unsigned int bE1 = __shfl(uE1, sl1, 64), bO1 = __shfl(uO1, sl1, 64);
        union { short8 s8; unsigned int uu[4]; } B2;
        B2.uu[0] = hiL ? aO0 : aE0;
        B2.uu[1] = hiL ? aO1 : aE1;
        B2.uu[2] = hiL ? bO0 : bE0;
        B2.uu[3] = hiL ? bO1 : bE1;
        #pragma unroll
        for (int nt2 = 0; nt2 < 4; ++nt2) {
            short8 wf2 = ((const short8*)lds_wb)[(nt2 * 4 + t) * 64 + lane];
            acc2[nt2] = __builtin_amdgcn_mfma_f32_16x16x32_bf16(wf2, B2.s8, acc2[nt2], 0, 0, 0);
        }
    }

    // ---- layer 3: per-lane partial dot, reduce across g groups ----
    float part = 0.f;
    #pragma unroll
    for (int nt2 = 0; nt2 < 4; ++nt2) {
        f32x4 wv = *(const f32x4*)&lds_w3[nt2 * 16 + g * 4];
        part += fmaxf(acc2[nt2][0], 0.f) * wv[0];
        part += fmaxf(acc2[nt2][1], 0.f) * wv[1];
        part += fmaxf(acc2[nt2][2], 0.f) * wv[2];
        part += fmaxf(acc2[nt2][3], 0.f) * wv[3];
    }
    part += __shfl_xor(part, 16, 64);
    part += __shfl_xor(part, 32, 64);   // all 4 g-copies of each j now hold the full dot

    const float h3 = fmaxf(part + b3v, 0.f);
    const float E = __expf(2.f * h3);
    const float Ec = (j >= i) ? E : 0.f;      // col contribution (incl diag)
    float Er = (j >  i) ? E : 0.f;            // row contribution (strict upper)

    Er += __shfl_xor(Er, 1, 64);
    Er += __shfl_xor(Er, 2, 64);
    Er += __shfl_xor(Er, 4, 64);
    Er += __shfl_xor(Er, 8, 64);
    Er += __shfl_xor(Er, 16, 64);
    Er += __shfl_xor(Er, 32, 64);             // 4 duplicated g-copies -> 4x row sum
    if (lane == 0)
        rowpart[((size_t)blk * NR + i) * 16 + jt16] = 0.25f * Er;

    if (lane < 16) lds_c[wave][lane] = Ec;    // g==0 copy
    __syncthreads();
    if (tid < 16) {
        float c = 0.f;
        #pragma unroll
        for (int w2 = 0; w2 < 8; ++w2) c += lds_c[w2][tid];
        // ragged colpart: valid it8 count for tile jt16 = 2*jt16+2
        colpart[(size_t)blk * 4352 + 16 * jt16 * (jt16 + 1) + tid * (2 * jt16 + 2) + it8] = c;
    }
}

// ---------------- agg stage 1 (+ fused colsoft): wc from colpart/rowpart, weighted X sums ----------------
__global__ __launch_bounds__(256) void agg_part_kernel(
    const float* __restrict__ X, const float* __restrict__ colpart,
    const float* __restrict__ rowpart, float* __restrict__ apart)
{
    const int dc = blockIdx.x, b = blockIdx.y, jc = blockIdx.z;
    const int tid = threadIdx.x;
    __shared__ float csh[2][256];
    __shared__ float red2[2][256];
    __shared__ float wc[32];

    {   // colsum[j] for both branches (symmetry: col part + row part)
        const int jt16 = tid >> 4, j16l = tid & 15;
        const int cnt = 2 * jt16 + 2;
        #pragma unroll
        for (int brx = 0; brx < 2; ++brx) {
            const int blk = brx * 4 + b;
            float cs = 0.f;
            const float* cp = colpart + (size_t)blk * 4352 + 16 * jt16 * (jt16 + 1) + j16l * cnt;
            for (int it2 = 0; it2 < cnt; ++it2) cs += cp[it2];
            const float* rp = rowpart + ((size_t)blk * NR + tid) * 16;
            for (int q = jt16; q < 16; ++q) cs += rp[q];
            csh[brx][tid] = cs;
            red2[brx][tid] = cs;
        }
    }
    __syncthreads();
    for (int s = 128; s > 0; s >>= 1) {
        if (tid < s) { red2[0][tid] += red2[0][tid + s]; red2[1][tid] += red2[1][tid + s]; }
        __syncthreads();
    }
    if (tid < 32) {
        int jx = jc * 32 + tid;
        wc[tid] = 0.5f * (csh[0][jx] / red2[0][0] + csh[1][jx] / red2[1][0]);
    }
    __syncthreads();

    const int d = dc * 256 + tid;
    if (d < 2052) {
        const float* xp = X + (size_t)b * NR * 2052 + (size_t)jc * 32 * 2052 + d;
        float a0 = 0.f, a1 = 0.f, a2 = 0.f, a3 = 0.f;
        for (int rr = 0; rr < 32; rr += 4) {
            a0 += wc[rr + 0] * xp[(size_t)(rr + 0) * 2052];
            a1 += wc[rr + 1] * xp[(size_t)(rr + 1) * 2052];
            a2 += wc[rr + 2] * xp[(size_t)(rr + 2) * 2052];
            a3 += wc[rr + 3] * xp[(size_t)(rr + 3) * 2052];
        }
        apart[(size_t)(jc * 4 + b) * 2304 + d] = (a0 + a1) + (a2 + a3);
    }
}

// ---------------- agg stage 2: sum partials ----------------
__global__ __launch_bounds__(256) void agg_final_kernel(
    const float* __restrict__ apart, float* __restrict__ out)
{
    const int dc = blockIdx.x, b = blockIdx.y;
    const int d = dc * 256 + threadIdx.x;
    if (d < 2052) {
        float s = 0.f;
        #pragma unroll
        for (int jc = 0; jc < 8; ++jc) s += apart[(size_t)(jc * 4 + b) * 2304 + d];
        out[b * 2052 + d] = s;
    }
}

extern "C" void kernel_launch(void* const* d_in, const int* in_sizes, int n_in,
                              void* d_out, int out_size, void* d_ws, size_t ws_size,
                              hipStream_t stream) {
    const float* Q   = (const float*)d_in[0];
    const float* X   = (const float*)d_in[1];
    const float* Wv  = (const float*)d_in[2];
    const float* bv  = (const float*)d_in[3];
    const float* Wq  = (const float*)d_in[4];
    const float* bq  = (const float*)d_in[5];
    const float* W01 = (const float*)d_in[6];
    const float* b01 = (const float*)d_in[7];
    const float* W02 = (const float*)d_in[8];
    const float* b02 = (const float*)d_in[9];
    const float* W03 = (const float*)d_in[10];
    const float* b03 = (const float*)d_in[11];
    const float* W1  = (const float*)d_in[12];
    const float* b1  = (const float*)d_in[13];
    const float* W2  = (const float*)d_in[14];
    const float* b2  = (const float*)d_in[15];
    const float* W3  = (const float*)d_in[16];
    const float* b3  = (const float*)d_in[17];

    char* ws = (char*)d_ws;
    // layout; aliases: wvp over colpart/rowpart region (dead before pairs writes),
    // apart over Xp (dead after pairs)
    float* Xp   = (float*)(ws + 0);              // 1,048,576 B
    float* Qpp  = (float*)(ws + 1048576);        //    16,384 B
    unsigned short* wpa = (unsigned short*)(ws + 1073152);  // 131,072 B
    unsigned short* wpb = (unsigned short*)(ws + 1204224);  //  32,768 B
    float* colpart = (float*)(ws + 1236992);     // 139,264 B  [8][4352] ragged
    float* rowpart = (float*)(ws + 1376256);     // 131,072 B  [8][256][16] -> end 1,507,328
    unsigned short* wvp = (unsigned short*)(ws + 1236992);  // 1,064,960 B (aliased, ends 2,301,952)
    float* apart = (float*)(ws + 0);             // 294,912 B (aliases Xp)
    float* out = (float*)d_out;

    setup_kernel<<<401, 256, 0, stream>>>(Q, Wq, Qpp, Wv, wvp,
                                          W01, W1, W02, W2, wpa, wpb);
    xp_kernel<<<dim3(16, 2, 4), 512, 0, stream>>>(X, wvp, bv, bq, Qpp, Xp);
    pairs_kernel<<<2176, 512, 0, stream>>>(Xp, wpa, wpb, b01, b02, b03,
                                           b1, b2, b3, W03, W3, colpart, rowpart);
    agg_part_kernel<<<dim3(9, 4, 8), 256, 0, stream>>>(X, colpart, rowpart, apart);
    agg_final_kernel<<<dim3(9, 4), 256, 0, stream>>>(apart, out);
}

// Round 13
// 100.936 us; speedup vs baseline: 1.0516x; 1.0516x over previous
//
#include <hip/hip_runtime.h>
#include <hip/hip_bf16.h>

typedef __attribute__((ext_vector_type(8)))  short short8;
typedef __attribute__((ext_vector_type(4)))  float f32x4;
typedef __attribute__((ext_vector_type(16))) float f32x16;

#define NR 256
#define CC 256

__device__ __forceinline__ unsigned short f2bf(float x) {
    union { float f; unsigned int u; } v; v.f = x;
    unsigned int r = v.u + 0x7FFFu + ((v.u >> 16) & 1u);
    return (unsigned short)(r >> 16);
}

__device__ __forceinline__ unsigned int pk2bf(float a, float b) {
    __hip_bfloat162 h = __float22bfloat162_rn(make_float2(a, b));
    union { __hip_bfloat162 h; unsigned int u; } cv; cv.h = h;
    return cv.u;
}

// ---------------- setup: qp (bx<16) | wvp_pack (bx<81) | mlp pack 32x32 layout (else) ----------------
__global__ __launch_bounds__(256) void setup_kernel(
    const float* __restrict__ Q, const float* __restrict__ Wq, float* __restrict__ Qpp,
    const float* __restrict__ Wv, unsigned short* __restrict__ wvp,
    const float* __restrict__ W01, const float* __restrict__ W1,
    const float* __restrict__ W02, const float* __restrict__ W2,
    unsigned short* __restrict__ wpa, unsigned short* __restrict__ wpb)
{
    __shared__ float tile[32][260];
    __shared__ float qs[256];
    const int bx = blockIdx.x;
    const int tid = threadIdx.x;

    if (bx < 16) {                       // ---- Qpp[ksl][b][n] = partial Q @ Wq
        int ksl = bx & 3, b = bx >> 2;
        qs[tid] = Q[b * 1024 + ksl * 256 + tid];
        __syncthreads();
        float acc = 0.f;
        #pragma unroll 4
        for (int d = 0; d < 256; ++d) acc += qs[d] * Wq[(size_t)(ksl * 256 + d) * 256 + tid];
        Qpp[(ksl * 4 + b) * 256 + tid] = acc;
    } else if (bx < 81) {                // ---- Wv -> 16x16x32 B-frag layout, K pad 2080
        int ks = bx - 16;                // 0..64
        for (int idx = tid; idx < 32 * 256; idx += 256) {
            int cr = idx >> 8, n = idx & 255;
            int c = ks * 32 + cr;
            tile[cr][n] = (c < 2056) ? Wv[(size_t)c * 256 + n] : 0.f;
        }
        __syncthreads();
        #pragma unroll
        for (int q = 0; q < 4; ++q) {
            int t2 = tid * 4 + q;
            int nt = t2 >> 6, l = t2 & 63;
            int gg = l >> 4, jj = l & 15;
            short8 s;
            #pragma unroll
            for (int e = 0; e < 8; ++e)
                s[e] = (short)f2bf(tile[gg * 8 + e][nt * 16 + jj]);
            *(short8*)&wvp[((size_t)(ks * 16 + nt) * 64 + l) * 8] = s;
        }
    } else {                             // ---- MLP weights -> 32x32x16 A-frag layout (r11-proven)
        // wpa: [br][nt1(4)][ks(16)][lane(64)][e(8)] = W[c=16ks+8*(l>>5)+e][n=32nt+(l&31)]
        // wpb: [br][nt2(2)][ks2(8)][lane(64)][e(8)] = W2[c=16ks2+8*(l>>5)+e][n=32nt2+(l&31)]
        int t = (bx - 81) * 256 + tid;   // < 81920
        if (t < 65536) {
            int e = t & 7, l = (t >> 3) & 63, ks = (t >> 9) & 15, nt = (t >> 13) & 3, br = (t >> 15) & 1;
            int cc = ks * 16 + (l >> 5) * 8 + e;
            int n = nt * 32 + (l & 31);
            const float* W = br ? W1 : W01;
            wpa[t] = f2bf(W[cc * 128 + n]);
        } else {
            int t2 = t - 65536;          // < 16384
            int e = t2 & 7, l = (t2 >> 3) & 63, ks = (t2 >> 9) & 7, nt = (t2 >> 12) & 1, br = (t2 >> 13) & 1;
            int cc = ks * 16 + (l >> 5) * 8 + e;
            int n = nt * 32 + (l & 31);
            const float* W = br ? W2 : W02;
            wpb[t2] = f2bf(W[cc * 64 + n]);
        }
    }
}

// ---------------- Xp (MFMA, 8-wave split-K); 64-col tiles, 256 blocks (1/CU), X read 4x ----------------
__global__ __launch_bounds__(512) void xp_kernel(
    const float* __restrict__ X, const unsigned short* __restrict__ wvp,
    const float* __restrict__ bv, const float* __restrict__ bq,
    const float* __restrict__ Qpp, float* __restrict__ Xp)
{
    __shared__ f32x4 red[8][4][65];
    const int tid = threadIdx.x;
    const int w = tid >> 6;           // 0..7
    const int lane = tid & 63;
    const int g = lane >> 4, j16v = lane & 15;
    const int mt = blockIdx.x;        // 16-row tile
    const int bn = blockIdx.y;        // 0..3 (64-col group)
    const int b  = blockIdx.z;

    const int i0 = mt * 16;
    const float* xrow = X + ((size_t)(b * NR) + (i0 + j16v)) * 2052;

    f32x4 acc[4] = {};

    for (int ks = w; ks < 64; ks += 8) {
        const int c0 = ks * 32 + g * 8;
        float4 xa = *(const float4*)(xrow + c0);
        float4 xb = *(const float4*)(xrow + c0 + 4);
        union { short8 s; unsigned int u[4]; } af;
        af.u[0] = pk2bf(xa.x, xa.y);
        af.u[1] = pk2bf(xa.z, xa.w);
        af.u[2] = pk2bf(xb.x, xb.y);
        af.u[3] = pk2bf(xb.z, xb.w);
        #pragma unroll
        for (int nt = 0; nt < 4; ++nt) {
            short8 bf = ((const short8*)wvp)[(size_t)(ks * 16 + bn * 4 + nt) * 64 + lane];
            acc[nt] = __builtin_amdgcn_mfma_f32_16x16x32_bf16(af.s, bf, acc[nt], 0, 0, 0);
        }
    }
    if (w == 0) {  // ks = 64 tail: c 2048..2079 (c>=2056 zero-weighted)
        float xv[8];
        #pragma unroll
        for (int e = 0; e < 8; ++e) {
            int q = g * 8 + e;
            int csrc = (q < 4) ? (2048 + q) : (q - 4);
            xv[e] = xrow[csrc];
        }
        union { short8 s; unsigned int u[4]; } af;
        af.u[0] = pk2bf(xv[0], xv[1]);
        af.u[1] = pk2bf(xv[2], xv[3]);
        af.u[2] = pk2bf(xv[4], xv[5]);
        af.u[3] = pk2bf(xv[6], xv[7]);
        #pragma unroll
        for (int nt = 0; nt < 4; ++nt) {
            short8 bf = ((const short8*)wvp)[(size_t)(64 * 16 + bn * 4 + nt) * 64 + lane];
            acc[nt] = __builtin_amdgcn_mfma_f32_16x16x32_bf16(af.s, bf, acc[nt], 0, 0, 0);
        }
    }
    #pragma unroll
    for (int nt = 0; nt < 4; ++nt) red[w][nt][lane] = acc[nt];
    __syncthreads();

    #pragma unroll
    for (int idx = tid; idx < 1024; idx += 512) {
        int nt = idx >> 8, rem = idx & 255;
        int l = rem & 63, reg = rem >> 6;
        float rsum = 0.f;
        #pragma unroll
        for (int ww = 0; ww < 8; ++ww) rsum += red[ww][nt][l][reg];
        int gg = l >> 4, jj = l & 15;
        int n = bn * 64 + nt * 16 + jj;
        float base = bv[n] + bq[n] + Qpp[b * 256 + n] + Qpp[(4 + b) * 256 + n]
                   + Qpp[(8 + b) * 256 + n] + Qpp[(12 + b) * 256 + n];
        int row = i0 + gg * 4 + reg;
        Xp[((b * NR) + row) * CC + n] = rsum + base;
    }
}

// ---------------- fused 3-layer MLP over pairs: r11 structure + K-split bfr + split w2r ----------------
// block = (b, br, it8 in [0,32), ONE jt in [it8/4, 8)). 1152 blocks. W1 fully LDS-resident.
// r11 was reg-capped at ~192 unified (bfr 64 + acc1 64 + acc2/w2r) -> 2.67 waves/SIMD (33%).
// Cuts (bitwise-identical arithmetic, same accumulation order):
//   (a) bfr built in two K-halves of 8 frags, register-reused (-32) -- W1 staging/barriers
//       unchanged (r12's K-split of the LDS STAGING is what regressed, not this);
//   (b) w2r loaded in two t-halves of 8 frags (-32 at peak).
// Peak ~140 regs -> ~14 waves/CU. LDS ~74.5KB -> 2 blocks/CU.
// __launch_bounds__(512,2): arch-VGPR cap 128 (r11 ran 64 arch at this bound, no spill).
__global__ __launch_bounds__(512, 2) void pairs_kernel(
    const float* __restrict__ Xp,
    const unsigned short* __restrict__ wpa,
    const unsigned short* __restrict__ wpb,
    const float* __restrict__ b01, const float* __restrict__ b02,
    const float* __restrict__ b03,
    const float* __restrict__ b1,  const float* __restrict__ b2,
    const float* __restrict__ b3,
    const float* __restrict__ W03, const float* __restrict__ W3,
    float* __restrict__ colpart, float* __restrict__ rowpart)
{
    __shared__ __align__(16) unsigned short lds_wa[32768];   // 64 KB: FULL W1 frags (this branch)
    __shared__ __align__(16) float lds_si[2048];             // 8 i-rows of Xp
    __shared__ __align__(16) float lds_bias1[128];
    __shared__ __align__(16) float lds_bias2[64];
    __shared__ __align__(16) float lds_w3[64];
    __shared__ float lds_c[8][33];

    const int tid = threadIdx.x;
    const int wave = tid >> 6;       // 0..7
    const int lane = tid & 63;
    const int hi = lane >> 5;        // 0/1: k-subgroup
    const int j32 = lane & 31;

    // grid decode: bx -> (b, br, it8, jt); 144 tiles per (b,br)
    int bx = blockIdx.x;
    int b = bx / 288;
    int r = bx - b * 288;
    int br = r / 144;
    int u = r - br * 144;
    int k = 0, off = 0;
    while (k < 7) {
        int cnt = 4 * (8 - k);            // blocks in group k
        if (u < off + cnt) break;
        off += cnt; ++k;
    }
    int rel = u - off;
    int it8 = 4 * k + rel / (8 - k);      // 0..31
    int jt  = k + rel % (8 - k);          // it8/4 .. 7

    const int i = it8 * 8 + wave;
    const int blk = br * 4 + b;
    const int j0 = jt * 32;
    const int j = j0 + j32;

    // each wave stages its OWN si row (wave-internal, no barrier needed before use)
    *(float4*)&lds_si[wave * 256 + lane * 4] =
        *(const float4*)&Xp[((b * NR) + i) * CC + lane * 4];

    // stage full branch W1 (64KB) + biases
    {
        const uint4* g1 = (const uint4*)(wpa + (size_t)br * 32768);
        uint4* s1 = (uint4*)lds_wa;
        #pragma unroll
        for (int kk = 0; kk < 8; ++kk) s1[kk * 512 + tid] = g1[kk * 512 + tid];
        if (tid < 128) lds_bias1[tid] = br ? b1[tid] : b01[tid];
        else if (tid < 192) lds_bias2[tid - 128] = br ? b2[tid - 128] : b02[tid - 128];
        else if (tid < 256) lds_w3[tid - 192] = br ? W3[tid - 192] : W03[tid - 192];
    }
    __syncthreads();
    const float b3v = br ? b3[0] : b03[0];
    const float* si = lds_si + wave * 256;
    const float* xr = Xp + ((size_t)(b * NR) + j) * CC;

    // acc1 init from bias1 (32x32 C/D: row = (reg&3)+8*(reg>>2)+4*hi)
    f32x16 acc1[4];
    #pragma unroll
    for (int t = 0; t < 4; ++t) {
        #pragma unroll
        for (int q = 0; q < 4; ++q) {
            const float* bb = &lds_bias1[t * 32 + q * 8 + hi * 4];
            acc1[t][q * 4 + 0] = bb[0];
            acc1[t][q * 4 + 1] = bb[1];
            acc1[t][q * 4 + 2] = bb[2];
            acc1[t][q * 4 + 3] = bb[3];
        }
    }

    // ---- layer 1, K-half 0: bfr[8] (ks 0..7), ks-outer / t-inner (4 indep chains) ----
    short8 bfr[8];
    #pragma unroll
    for (int ksl = 0; ksl < 8; ++ksl) {
        const int c0 = ksl * 16 + hi * 8;
        float4 xa = *(const float4*)(xr + c0);
        float4 xb = *(const float4*)(xr + c0 + 4);
        float4 sa = *(const float4*)(si + c0);
        float4 sb = *(const float4*)(si + c0 + 4);
        union { short8 s; unsigned int uu[4]; } f;
        f.uu[0] = pk2bf(xa.x * sa.x, xa.y * sa.y);
        f.uu[1] = pk2bf(xa.z * sa.z, xa.w * sa.w);
        f.uu[2] = pk2bf(xb.x * sb.x, xb.y * sb.y);
        f.uu[3] = pk2bf(xb.z * sb.z, xb.w * sb.w);
        bfr[ksl] = f.s;
    }
    #pragma unroll
    for (int ksl = 0; ksl < 8; ++ksl) {
        const short8 bb = bfr[ksl];
        #pragma unroll
        for (int t = 0; t < 4; ++t) {
            short8 wf = ((const short8*)lds_wa)[(t * 16 + ksl) * 64 + lane];
            acc1[t] = __builtin_amdgcn_mfma_f32_32x32x16_bf16(wf, bb, acc1[t], 0, 0, 0);
        }
    }

    // ---- layer 1, K-half 1: rebuild bfr (ks 8..15), register reuse ----
    #pragma unroll
    for (int ksl = 0; ksl < 8; ++ksl) {
        const int c0 = (8 + ksl) * 16 + hi * 8;
        float4 xa = *(const float4*)(xr + c0);
        float4 xb = *(const float4*)(xr + c0 + 4);
        float4 sa = *(const float4*)(si + c0);
        float4 sb = *(const float4*)(si + c0 + 4);
        union { short8 s; unsigned int uu[4]; } f;
        f.uu[0] = pk2bf(xa.x * sa.x, xa.y * sa.y);
        f.uu[1] = pk2bf(xa.z * sa.z, xa.w * sa.w);
        f.uu[2] = pk2bf(xb.x * sb.x, xb.y * sb.y);
        f.uu[3] = pk2bf(xb.z * sb.z, xb.w * sb.w);
        bfr[ksl] = f.s;
    }
    #pragma unroll
    for (int ksl = 0; ksl < 8; ++ksl) {
        const short8 bb = bfr[ksl];
        #pragma unroll
        for (int t = 0; t < 4; ++t) {
            short8 wf = ((const short8*)lds_wa)[(t * 16 + 8 + ksl) * 64 + lane];
            acc1[t] = __builtin_amdgcn_mfma_f32_32x32x16_bf16(wf, bb, acc1[t], 0, 0, 0);
        }
    }

    // ---- layer 2: relu + pack + lane^32 exchange; w2r in two t-halves ----
    f32x16 acc2[2];
    #pragma unroll
    for (int nt = 0; nt < 2; ++nt) {
        #pragma unroll
        for (int q = 0; q < 4; ++q) {
            const float* bb = &lds_bias2[nt * 32 + q * 8 + hi * 4];
            acc2[nt][q * 4 + 0] = bb[0];
            acc2[nt][q * 4 + 1] = bb[1];
            acc2[nt][q * 4 + 2] = bb[2];
            acc2[nt][q * 4 + 3] = bb[3];
        }
    }
    const short8* wb = (const short8*)wpb + (size_t)br * 1024;

    short8 w2r[8];
    // first half: ks2 0..3 (nt2=0 at wb[ks2], nt2=1 at wb[8+ks2])
    #pragma unroll
    for (int q = 0; q < 4; ++q) {
        w2r[q]     = wb[q * 64 + lane];
        w2r[4 + q] = wb[(8 + q) * 64 + lane];
    }
    #pragma unroll
    for (int t = 0; t < 2; ++t) {
        #pragma unroll
        for (int s = 0; s < 2; ++s) {
            const int bse = s * 8;
            float rA0 = fmaxf(acc1[t][bse + 0], 0.f), rA1 = fmaxf(acc1[t][bse + 1], 0.f);
            float rA2 = fmaxf(acc1[t][bse + 2], 0.f), rA3 = fmaxf(acc1[t][bse + 3], 0.f);
            float rB0 = fmaxf(acc1[t][bse + 4], 0.f), rB1 = fmaxf(acc1[t][bse + 5], 0.f);
            float rB2 = fmaxf(acc1[t][bse + 6], 0.f), rB3 = fmaxf(acc1[t][bse + 7], 0.f);
            unsigned int uA0 = pk2bf(rA0, rA1), uA1 = pk2bf(rA2, rA3);
            unsigned int uB0 = pk2bf(rB0, rB1), uB1 = pk2bf(rB2, rB3);
            unsigned int pA0 = __shfl_xor(uA0, 32, 64), pA1 = __shfl_xor(uA1, 32, 64);
            unsigned int pB0 = __shfl_xor(uB0, 32, 64), pB1 = __shfl_xor(uB1, 32, 64);
            union { short8 s8; unsigned int uu[4]; } B2;
            B2.uu[0] = hi ? pB0 : uA0;
            B2.uu[1] = hi ? pB1 : uA1;
            B2.uu[2] = hi ? uB0 : pA0;
            B2.uu[3] = hi ? uB1 : pA1;
            const int ks2 = 2 * t + s;    // 0..3
            acc2[0] = __builtin_amdgcn_mfma_f32_32x32x16_bf16(w2r[ks2], B2.s8, acc2[0], 0, 0, 0);
            acc2[1] = __builtin_amdgcn_mfma_f32_32x32x16_bf16(w2r[4 + ks2], B2.s8, acc2[1], 0, 0, 0);
        }
    }
    // second half: ks2 4..7
    #pragma unroll
    for (int q = 0; q < 4; ++q) {
        w2r[q]     = wb[(4 + q) * 64 + lane];
        w2r[4 + q] = wb[(12 + q) * 64 + lane];
    }
    #pragma unroll
    for (int t = 2; t < 4; ++t) {
        #pragma unroll
        for (int s = 0; s < 2; ++s) {
            const int bse = s * 8;
            float rA0 = fmaxf(acc1[t][bse + 0], 0.f), rA1 = fmaxf(acc1[t][bse + 1], 0.f);
            float rA2 = fmaxf(acc1[t][bse + 2], 0.f), rA3 = fmaxf(acc1[t][bse + 3], 0.f);
            float rB0 = fmaxf(acc1[t][bse + 4], 0.f), rB1 = fmaxf(acc1[t][bse + 5], 0.f);
            float rB2 = fmaxf(acc1[t][bse + 6], 0.f), rB3 = fmaxf(acc1[t][bse + 7], 0.f);
            unsigned int uA0 = pk2bf(rA0, rA1), uA1 = pk2bf(rA2, rA3);
            unsigned int uB0 = pk2bf(rB0, rB1), uB1 = pk2bf(rB2, rB3);
            unsigned int pA0 = __shfl_xor(uA0, 32, 64), pA1 = __shfl_xor(uA1, 32, 64);
            unsigned int pB0 = __shfl_xor(uB0, 32, 64), pB1 = __shfl_xor(uB1, 32, 64);
            union { short8 s8; unsigned int uu[4]; } B2;
            B2.uu[0] = hi ? pB0 : uA0;
            B2.uu[1] = hi ? pB1 : uA1;
            B2.uu[2] = hi ? uB0 : pA0;
            B2.uu[3] = hi ? uB1 : pA1;
            const int ks2 = 2 * t + s - 4;    // 0..3 within this half
            acc2[0] = __builtin_amdgcn_mfma_f32_32x32x16_bf16(w2r[ks2], B2.s8, acc2[0], 0, 0, 0);
            acc2[1] = __builtin_amdgcn_mfma_f32_32x32x16_bf16(w2r[4 + ks2], B2.s8, acc2[1], 0, 0, 0);
        }
    }

    // ---- layer 3: per-lane partial dot, reduce across hi pair ----
    float part = 0.f;
    #pragma unroll
    for (int nt = 0; nt < 2; ++nt) {
        #pragma unroll
        for (int q = 0; q < 4; ++q) {
            const float* wv = &lds_w3[nt * 32 + q * 8 + hi * 4];
            part += fmaxf(acc2[nt][q * 4 + 0], 0.f) * wv[0];
            part += fmaxf(acc2[nt][q * 4 + 1], 0.f) * wv[1];
            part += fmaxf(acc2[nt][q * 4 + 2], 0.f) * wv[2];
            part += fmaxf(acc2[nt][q * 4 + 3], 0.f) * wv[3];
        }
    }
    part += __shfl_xor(part, 32, 64);
    const float h3 = fmaxf(part + b3v, 0.f);
    const float E = __expf(2.f * h3);
    const float Ec = (j >= i) ? E : 0.f;      // col contribution (incl diag)
    float Er = (j >  i) ? E : 0.f;            // row contribution (strict upper)

    Er += __shfl_xor(Er, 1, 64);
    Er += __shfl_xor(Er, 2, 64);
    Er += __shfl_xor(Er, 4, 64);
    Er += __shfl_xor(Er, 8, 64);
    Er += __shfl_xor(Er, 16, 64);
    Er += __shfl_xor(Er, 32, 64);             // duplicated hi halves -> 2x row sum
    if (lane == 0)
        rowpart[((size_t)blk * NR + i) * 8 + jt] = 0.5f * Er;

    if (!hi) lds_c[wave][j32] = Ec;
    __syncthreads();
    if (tid < 32) {
        float c = 0.f;
        #pragma unroll
        for (int wv2 = 0; wv2 < 8; ++wv2) c += lds_c[wv2][tid];
        // ragged colpart: per (j, it8) slot; valid it8 count for tile jt = 4jt+4
        colpart[(size_t)blk * 4608 + 64 * jt * (jt + 1) + tid * (4 * jt + 4) + it8] = c;
    }
}

// ---------------- agg stage 1 (+ fused colsoft): wc from colpart/rowpart, weighted X sums ----------------
__global__ __launch_bounds__(256) void agg_part_kernel(
    const float* __restrict__ X, const float* __restrict__ colpart,
    const float* __restrict__ rowpart, float* __restrict__ apart)
{
    const int dc = blockIdx.x, b = blockIdx.y, jc = blockIdx.z;
    const int tid = threadIdx.x;
    __shared__ float csh[2][256];
    __shared__ float red2[2][256];
    __shared__ float wc[32];

    {   // colsum[j] for both branches (symmetry: col part + row part), r11 ragged layout
        const int jt = tid >> 5, j32l = tid & 31;
        const int cnt = 4 * jt + 4;
        #pragma unroll
        for (int brx = 0; brx < 2; ++brx) {
            const int blk = brx * 4 + b;
            float cs = 0.f;
            const float* cp = colpart + (size_t)blk * 4608 + 64 * jt * (jt + 1) + j32l * cnt;
            for (int it2 = 0; it2 < cnt; ++it2) cs += cp[it2];
            const float* rp = rowpart + ((size_t)blk * NR + tid) * 8;
            for (int q = jt; q < 8; ++q) cs += rp[q];
            csh[brx][tid] = cs;
            red2[brx][tid] = cs;
        }
    }
    __syncthreads();
    for (int s = 128; s > 0; s >>= 1) {
        if (tid < s) { red2[0][tid] += red2[0][tid + s]; red2[1][tid] += red2[1][tid + s]; }
        __syncthreads();
    }
    if (tid < 32) {
        int jx = jc * 32 + tid;
        wc[tid] = 0.5f * (csh[0][jx] / red2[0][0] + csh[1][jx] / red2[1][0]);
    }
    __syncthreads();

    const int d = dc * 256 + tid;
    if (d < 2052) {
        const float* xp = X + (size_t)b * NR * 2052 + (size_t)jc * 32 * 2052 + d;
        float a0 = 0.f, a1 = 0.f, a2 = 0.f, a3 = 0.f;
        for (int rr = 0; rr < 32; rr += 4) {
            a0 += wc[rr + 0] * xp[(size_t)(rr + 0) * 2052];
            a1 += wc[rr + 1] * xp[(size_t)(rr + 1) * 2052];
            a2 += wc[rr + 2] * xp[(size_t)(rr + 2) * 2052];
            a3 += wc[rr + 3] * xp[(size_t)(rr + 3) * 2052];
        }
        apart[(size_t)(jc * 4 + b) * 2304 + d] = (a0 + a1) + (a2 + a3);
    }
}

// ---------------- agg stage 2: sum partials ----------------
__global__ __launch_bounds__(256) void agg_final_kernel(
    const float* __restrict__ apart, float* __restrict__ out)
{
    const int dc = blockIdx.x, b = blockIdx.y;
    const int d = dc * 256 + threadIdx.x;
    if (d < 2052) {
        float s = 0.f;
        #pragma unroll
        for (int jc = 0; jc < 8; ++jc) s += apart[(size_t)(jc * 4 + b) * 2304 + d];
        out[b * 2052 + d] = s;
    }
}

extern "C" void kernel_launch(void* const* d_in, const int* in_sizes, int n_in,
                              void* d_out, int out_size, void* d_ws, size_t ws_size,
                              hipStream_t stream) {
    const float* Q   = (const float*)d_in[0];
    const float* X   = (const float*)d_in[1];
    const float* Wv  = (const float*)d_in[2];
    const float* bv  = (const float*)d_in[3];
    const float* Wq  = (const float*)d_in[4];
    const float* bq  = (const float*)d_in[5];
    const float* W01 = (const float*)d_in[6];
    const float* b01 = (const float*)d_in[7];
    const float* W02 = (const float*)d_in[8];
    const float* b02 = (const float*)d_in[9];
    const float* W03 = (const float*)d_in[10];
    const float* b03 = (const float*)d_in[11];
    const float* W1  = (const float*)d_in[12];
    const float* b1  = (const float*)d_in[13];
    const float* W2  = (const float*)d_in[14];
    const float* b2  = (const float*)d_in[15];
    const float* W3  = (const float*)d_in[16];
    const float* b3  = (const float*)d_in[17];

    char* ws = (char*)d_ws;
    // layout; aliases: wvp over colpart/rowpart region (dead before pairs writes),
    // apart over Xp (dead after pairs)
    float* Xp   = (float*)(ws + 0);              // 1,048,576 B
    float* Qpp  = (float*)(ws + 1048576);        //    16,384 B
    unsigned short* wpa = (unsigned short*)(ws + 1073152);  // 131,072 B
    unsigned short* wpb = (unsigned short*)(ws + 1204224);  //  32,768 B
    float* colpart = (float*)(ws + 1236992);     // 147,456 B  [8][4608] ragged
    float* rowpart = (float*)(ws + 1384448);     //  65,536 B  [8][256][8] -> end 1,449,984
    unsigned short* wvp = (unsigned short*)(ws + 1236992);  // 1,064,960 B (aliased, ends 2,301,952)
    float* apart = (float*)(ws + 0);             // 294,912 B (aliases Xp)
    float* out = (float*)d_out;

    setup_kernel<<<401, 256, 0, stream>>>(Q, Wq, Qpp, Wv, wvp,
                                          W01, W1, W02, W2, wpa, wpb);
    xp_kernel<<<dim3(16, 4, 4), 512, 0, stream>>>(X, wvp, bv, bq, Qpp, Xp);
    pairs_kernel<<<1152, 512, 0, stream>>>(Xp, wpa, wpb, b01, b02, b03,
                                           b1, b2, b3, W03, W3, colpart, rowpart);
    agg_part_kernel<<<dim3(9, 4, 8), 256, 0, stream>>>(X, colpart, rowpart, apart);
    agg_final_kernel<<<dim3(9, 4), 256, 0, stream>>>(apart, out);
}